// Round 20
// baseline (18.738 us; speedup 1.0000x reference)
//
#include <hip/hip_runtime.h>

#define IMG    512
#define BAND   4            // output rows per wave
#define NBLK   512          // 4 waves per block; 2048 bands total
#define NPIX   (16.0 * 512.0 * 512.0)
#define EPS    1e-5f
#define INV81  (1.0f / 81.0f)

struct Rows { float4 i0, i1, j0, j1; };

__device__ __forceinline__ Rows load_rows(const float* __restrict__ Ib,
                                          const float* __restrict__ Jb,
                                          int y, int col0)
{
    Rows r;
    if (y >= 0 && y < IMG) {          // wave-uniform (y uniform per wave)
        const float* rI = Ib + (size_t)y * IMG + col0;
        const float* rJ = Jb + (size_t)y * IMG + col0;
        r.i0 = *(const float4*)(rI);
        r.i1 = *(const float4*)(rI + 4);
        r.j0 = *(const float4*)(rJ);
        r.j1 = *(const float4*)(rJ + 4);
    } else {
        r.i0 = r.i1 = r.j0 = r.j1 = float4{0.f, 0.f, 0.f, 0.f};
    }
    return r;
}

#define ACC(c, xv, yv)                          \
    sI[c]  += (xv); sJ[c] += (yv);              \
    sII[c]  = fmaf((xv), (xv), sII[c]);         \
    sJJ[c]  = fmaf((yv), (yv), sJJ[c]);         \
    sIJ[c]  = fmaf((xv), (yv), sIJ[c]);

#define UPD(c, nx, ny, ox, oy)                                  \
    sI[c]  += (nx) - (ox);                                      \
    sJ[c]  += (ny) - (oy);                                      \
    sII[c]  = fmaf((nx), (nx), fmaf(-(ox), (ox), sII[c]));      \
    sJJ[c]  = fmaf((ny), (ny), fmaf(-(oy), (oy), sJJ[c]));      \
    sIJ[c]  = fmaf((nx), (ny), fmaf(-(ox), (oy), sIJ[c]));

// NOTE: parameter must NOT be named `w` — the body's `.w` member accesses
// would be macro-substituted (round 4's compile failure).
#define ACC_ROWS(R)                              \
    ACC(0, R.i0.x, R.j0.x) ACC(1, R.i0.y, R.j0.y)\
    ACC(2, R.i0.z, R.j0.z) ACC(3, R.i0.w, R.j0.w)\
    ACC(4, R.i1.x, R.j1.x) ACC(5, R.i1.y, R.j1.y)\
    ACC(6, R.i1.z, R.j1.z) ACC(7, R.i1.w, R.j1.w)

#define UPD_ROWS(NR, OR)                                                  \
    UPD(0, NR.i0.x, NR.j0.x, OR.i0.x, OR.j0.x)                            \
    UPD(1, NR.i0.y, NR.j0.y, OR.i0.y, OR.j0.y)                            \
    UPD(2, NR.i0.z, NR.j0.z, OR.i0.z, OR.j0.z)                            \
    UPD(3, NR.i0.w, NR.j0.w, OR.i0.w, OR.j0.w)                            \
    UPD(4, NR.i1.x, NR.j1.x, OR.i1.x, OR.j1.x)                            \
    UPD(5, NR.i1.y, NR.j1.y, OR.i1.y, OR.j1.y)                            \
    UPD(6, NR.i1.z, NR.j1.z, OR.i1.z, OR.j1.z)                            \
    UPD(7, NR.i1.w, NR.j1.w, OR.i1.w, OR.j1.w)

// Horizontal 9-window over one quantity's 8 column-sums — BYTE-IDENTICAL
// to the round-13 passing form (round 18's hoisted-halo rewrite failed
// absmax; bisecting). Halos from neighbor lanes via __shfl; lane 0/63
// masked to zero == image zero-padding.
__device__ __forceinline__ void hwin(const float s[8], int lane, float w[8])
{
    float l[4], r[4];
    #pragma unroll
    for (int i = 0; i < 4; ++i) {
        float lv = __shfl_up(s[4 + i], 1, 64);
        float rv = __shfl_down(s[i],   1, 64);
        l[i] = (lane == 0)  ? 0.f : lv;
        r[i] = (lane == 63) ? 0.f : rv;
    }
    w[0] = ((l[0] + l[1]) + (l[2] + l[3])) +
           ((s[0] + s[1]) + (s[2] + s[3])) + s[4];
    w[1] = w[0] + s[5] - l[0];
    w[2] = w[1] + s[6] - l[1];
    w[3] = w[2] + s[7] - l[2];
    w[4] = w[3] + r[0] - l[3];
    w[5] = w[4] + r[1] - s[0];
    w[6] = w[5] + r[2] - s[1];
    w[7] = w[6] + r[3] - s[2];
}

// BISECTION ROUND: compute path = round 13 exactly (passing, 18.66us).
// ONLY change: finalize tail. LDS block-reduce of the 4 wave partials ->
// ONE exchange per block (512 slots, was 2048); tid0-only vmcnt drain +
// residue counter; last block reads 2 slots/thread (was 8 sequential
// coherent-point RMWs). If this fails -> block-tail protocol race; revert.
// Cross-block protocol = atomic RMWs only (round 11): exchange publish,
// fetch_add residue counter, fetch_add(0.0) read-back. No acq/rel fences
// (round 9: chip-wide L2 writeback/inv, 2.3x).
__global__ __launch_bounds__(256) void ncc_band_kernel(
    const float* __restrict__ I, const float* __restrict__ J,
    double* __restrict__ slots, unsigned int* __restrict__ counter,
    float* __restrict__ out)
{
    const int lane = threadIdx.x & 63;
    const int wid  = threadIdx.x >> 6;
    // bijective XCD swizzle over 512 blocks (512 % 8 == 0):
    // XCD k gets a contiguous 256-band chunk (2 images ~ its 4MB L2).
    const int sblk = (blockIdx.x & 7) * (NBLK / 8) + (blockIdx.x >> 3);
    const int band = sblk * 4 + wid;              // 0..2047
    const int img  = band >> 7;                   // 128 bands / image
    const int y0   = (band & 127) * BAND;
    const int col0 = lane * 8;

    const float* Ib = I + (size_t)img * IMG * IMG;
    const float* Jb = J + (size_t)img * IMG * IMG;

    float sI[8], sJ[8], sII[8], sJJ[8], sIJ[8];
    #pragma unroll
    for (int c = 0; c < 8; ++c) { sI[c]=0.f; sJ[c]=0.f; sII[c]=0.f; sJJ[c]=0.f; sIJ[c]=0.f; }

    // ---- warm-up rows y0-4..y0+4: 4 loads in flight up front, then
    //      2-deep ping-pong. od0/od1 stay live until their UPDs. ----
    Rows od0 = load_rows(Ib, Jb, y0 - 4, col0);   // held
    Rows od1 = load_rows(Ib, Jb, y0 - 3, col0);   // held
    Rows A   = load_rows(Ib, Jb, y0 - 2, col0);
    Rows B   = load_rows(Ib, Jb, y0 - 1, col0);

    ACC_ROWS(od0)
    ACC_ROWS(od1)
    ACC_ROWS(A)  A = load_rows(Ib, Jb, y0 + 0, col0);
    ACC_ROWS(B)  B = load_rows(Ib, Jb, y0 + 1, col0);
    ACC_ROWS(A)  A = load_rows(Ib, Jb, y0 + 2, col0);
    ACC_ROWS(B)  B = load_rows(Ib, Jb, y0 + 3, col0);
    ACC_ROWS(A)  A = load_rows(Ib, Jb, y0 + 4, col0);
    ACC_ROWS(B)  B = load_rows(Ib, Jb, y0 + 5, col0);   // nw0
    ACC_ROWS(A)  A = load_rows(Ib, Jb, y0 + 6, col0);   // nw1
    // sums now cover rows y0-4..y0+4; B=row y0+5, A=row y0+6 in flight.

    float local = 0.0f;

    // lean hpass: one shared transient, wI/wJ reused for Iv/Jv
    // (round-13 form, proven absmax-0)
    auto hpass = [&]() {
        float wI[8], wJ[8], t[8], cross[8];
        hwin(sI, lane, wI);
        hwin(sJ, lane, wJ);
        hwin(sIJ, lane, t);
        #pragma unroll
        for (int k = 0; k < 8; ++k)
            cross[k] = fmaxf(fmaf(-wI[k] * INV81, wJ[k], t[k]), EPS);
        hwin(sII, lane, t);
        #pragma unroll
        for (int k = 0; k < 8; ++k)
            wI[k] = fmaxf(fmaf(-wI[k] * INV81, wI[k], t[k]), EPS);   // Iv
        hwin(sJJ, lane, t);
        #pragma unroll
        for (int k = 0; k < 8; ++k)
            wJ[k] = fmaxf(fmaf(-wJ[k] * INV81, wJ[k], t[k]), EPS);   // Jv
        #pragma unroll
        for (int k = 0; k < 8; ++k)
            local += (cross[k] * cross[k]) * __builtin_amdgcn_rcpf(wI[k] * wJ[k]);
    };

    hpass();                               // row y0      (covers B,A loads)
    UPD_ROWS(B, od0)                       // +y0+5, -y0-4 (od0 freed)
    B = load_rows(Ib, Jb, y0 + 7, col0);   // nw2
    hpass();                               // row y0+1
    UPD_ROWS(A, od1)                       // +y0+6, -y0-3 (od1 freed)
    A = load_rows(Ib, Jb, y0 - 2, col0);   // od2 re-read (L2-resident)
    hpass();                               // row y0+2
    UPD_ROWS(B, A)                         // +y0+7, -y0-2
    hpass();                               // row y0+3

    // ---- wave reduction ----
    #pragma unroll
    for (int off = 32; off > 0; off >>= 1)
        local += __shfl_down(local, off, 64);

    // ---- NEW TAIL: block reduce in LDS -> ONE exchange per block ----
    __shared__ float wpart[4];
    __shared__ bool  amLast;
    if (lane == 0) wpart[wid] = local;
    __syncthreads();
    if (threadIdx.x == 0) {
        double bsum = ((double)wpart[0] + (double)wpart[1]) +
                      ((double)wpart[2] + (double)wpart[3]);
        double old = __hip_atomic_exchange(&slots[blockIdx.x], bsum,
                                           __ATOMIC_RELAXED,
                                           __HIP_MEMORY_SCOPE_AGENT);
        asm volatile("" :: "v"(old));          // keep the returning RMW live
        asm volatile("s_waitcnt vmcnt(0)" ::: "memory");  // ack == coherent
        unsigned int oc = __hip_atomic_fetch_add(
            counter, 1u, __ATOMIC_RELAXED, __HIP_MEMORY_SCOPE_AGENT);
        amLast = ((oc & (NBLK - 1)) == NBLK - 1);
    }
    __syncthreads();

    // ---- last block reduces 512 block-slots via idempotent RMW reads ----
    if (amLast) {
        const int tid = threadIdx.x;
        double t = __hip_atomic_fetch_add(&slots[tid], 0.0,
                                          __ATOMIC_RELAXED,
                                          __HIP_MEMORY_SCOPE_AGENT);
        t += __hip_atomic_fetch_add(&slots[tid + 256], 0.0,
                                    __ATOMIC_RELAXED,
                                    __HIP_MEMORY_SCOPE_AGENT);
        #pragma unroll
        for (int off = 32; off > 0; off >>= 1)
            t += __shfl_down(t, off, 64);

        __shared__ double wsumd[4];
        if ((tid & 63) == 0) wsumd[tid >> 6] = t;
        __syncthreads();
        if (tid == 0)
            out[0] = (float)(-((wsumd[0] + wsumd[1]) +
                               (wsumd[2] + wsumd[3])) / NPIX);
    }
}

extern "C" void kernel_launch(void* const* d_in, const int* in_sizes, int n_in,
                              void* d_out, int out_size, void* d_ws, size_t ws_size,
                              hipStream_t stream)
{
    const float* I = (const float*)d_in[0];   // y_true
    const float* J = (const float*)d_in[1];   // y_pred
    float* out = (float*)d_out;
    double* slots = (double*)d_ws;                 // 512 doubles (per block)
    unsigned int* counter = (unsigned int*)(slots + NBLK);  // next 4 bytes

    // single dispatch: 512 blocks x 256 threads
    ncc_band_kernel<<<NBLK, 256, 0, stream>>>(I, J, slots, counter, out);
}

// Round 25
// 16.158 us; speedup vs baseline: 1.1596x; 1.1596x over previous
//
#include <hip/hip_runtime.h>

#define IMG    512
#define BAND   4            // output rows per wave
#define NBLK   512          // 4 waves per block; 2048 bands total
#define NPIX   (16.0 * 512.0 * 512.0)
#define EPS    1e-5f
#define INV81  (1.0f / 81.0f)

struct Rows { float4 i0, i1, j0, j1; };

__device__ __forceinline__ Rows load_rows(const float* __restrict__ Ib,
                                          const float* __restrict__ Jb,
                                          int y, int col0)
{
    Rows r;
    if (y >= 0 && y < IMG) {          // wave-uniform (y uniform per wave)
        const float* rI = Ib + (size_t)y * IMG + col0;
        const float* rJ = Jb + (size_t)y * IMG + col0;
        r.i0 = *(const float4*)(rI);
        r.i1 = *(const float4*)(rI + 4);
        r.j0 = *(const float4*)(rJ);
        r.j1 = *(const float4*)(rJ + 4);
    } else {
        r.i0 = r.i1 = r.j0 = r.j1 = float4{0.f, 0.f, 0.f, 0.f};
    }
    return r;
}

#define ACC(c, xv, yv)                          \
    sI[c]  += (xv); sJ[c] += (yv);              \
    sII[c]  = fmaf((xv), (xv), sII[c]);         \
    sJJ[c]  = fmaf((yv), (yv), sJJ[c]);         \
    sIJ[c]  = fmaf((xv), (yv), sIJ[c]);

#define UPD(c, nx, ny, ox, oy)                                  \
    sI[c]  += (nx) - (ox);                                      \
    sJ[c]  += (ny) - (oy);                                      \
    sII[c]  = fmaf((nx), (nx), fmaf(-(ox), (ox), sII[c]));      \
    sJJ[c]  = fmaf((ny), (ny), fmaf(-(oy), (oy), sJJ[c]));      \
    sIJ[c]  = fmaf((nx), (ny), fmaf(-(ox), (oy), sIJ[c]));

// NOTE: parameter must NOT be named `w` — the body's `.w` member accesses
// would be macro-substituted (round 4's compile failure).
#define ACC_ROWS(R)                              \
    ACC(0, R.i0.x, R.j0.x) ACC(1, R.i0.y, R.j0.y)\
    ACC(2, R.i0.z, R.j0.z) ACC(3, R.i0.w, R.j0.w)\
    ACC(4, R.i1.x, R.j1.x) ACC(5, R.i1.y, R.j1.y)\
    ACC(6, R.i1.z, R.j1.z) ACC(7, R.i1.w, R.j1.w)

#define UPD_ROWS(NR, OR)                                                  \
    UPD(0, NR.i0.x, NR.j0.x, OR.i0.x, OR.j0.x)                            \
    UPD(1, NR.i0.y, NR.j0.y, OR.i0.y, OR.j0.y)                            \
    UPD(2, NR.i0.z, NR.j0.z, OR.i0.z, OR.j0.z)                            \
    UPD(3, NR.i0.w, NR.j0.w, OR.i0.w, OR.j0.w)                            \
    UPD(4, NR.i1.x, NR.j1.x, OR.i1.x, OR.j1.x)                            \
    UPD(5, NR.i1.y, NR.j1.y, OR.i1.y, OR.j1.y)                            \
    UPD(6, NR.i1.z, NR.j1.z, OR.i1.z, OR.j1.z)                            \
    UPD(7, NR.i1.w, NR.j1.w, OR.i1.w, OR.j1.w)

// Horizontal 9-window over one quantity's 8 column-sums — PROVEN form
// (rounds 13/19). 8 shuffles consumed immediately; lane 0/63 masked to
// zero == image zero-padding.
__device__ __forceinline__ void hwin(const float s[8], int lane, float w[8])
{
    float l[4], r[4];
    #pragma unroll
    for (int i = 0; i < 4; ++i) {
        float lv = __shfl_up(s[4 + i], 1, 64);
        float rv = __shfl_down(s[i],   1, 64);
        l[i] = (lane == 0)  ? 0.f : lv;
        r[i] = (lane == 63) ? 0.f : rv;
    }
    w[0] = ((l[0] + l[1]) + (l[2] + l[3])) +
           ((s[0] + s[1]) + (s[2] + s[3])) + s[4];
    w[1] = w[0] + s[5] - l[0];
    w[2] = w[1] + s[6] - l[1];
    w[3] = w[2] + s[7] - l[2];
    w[4] = w[3] + r[0] - l[3];
    w[5] = w[4] + r[1] - s[0];
    w[6] = w[5] + r[2] - s[1];
    w[7] = w[6] + r[3] - s[2];
}

// TWO-DISPATCH STRUCTURE (kernel-boundary coherence — the only cross-block
// sync mechanism with a perfect correctness record here). ROUND-23 LESSON:
// the fused last-block tail with relaxed agent-scope atomic RMWs is
// NONDETERMINISTICALLY racy on gfx950 — identical source passed r19,
// failed r23. Per-XCD L2 non-coherence can lose slot publishes without
// acquire/release cache ops; with them (r9) the L2 flushes cost 2.3x.
// So: no atomics, no fences, no counters. Block partial -> plain store;
// separate finalize kernel (stream order provides release/acquire).
__global__ __launch_bounds__(256) void ncc_band_kernel(
    const float* __restrict__ I, const float* __restrict__ J,
    double* __restrict__ slots)
{
    const int lane = threadIdx.x & 63;
    const int wid  = threadIdx.x >> 6;
    // bijective XCD swizzle over 512 blocks (512 % 8 == 0):
    // XCD k gets a contiguous 256-band chunk (2 images ~ its 4MB L2).
    const int sblk = (blockIdx.x & 7) * (NBLK / 8) + (blockIdx.x >> 3);
    const int band = sblk * 4 + wid;              // 0..2047
    const int img  = band >> 7;                   // 128 bands / image
    const int y0   = (band & 127) * BAND;
    const int col0 = lane * 8;

    const float* Ib = I + (size_t)img * IMG * IMG;
    const float* Jb = J + (size_t)img * IMG * IMG;

    float sI[8], sJ[8], sII[8], sJJ[8], sIJ[8];
    #pragma unroll
    for (int c = 0; c < 8; ++c) { sI[c]=0.f; sJ[c]=0.f; sII[c]=0.f; sJJ[c]=0.f; sIJ[c]=0.f; }

    // ---- warm-up rows y0-4..y0+4: 4 loads in flight up front, then
    //      2-deep ping-pong. od0/od1 stay live until their UPDs. ----
    Rows od0 = load_rows(Ib, Jb, y0 - 4, col0);   // held
    Rows od1 = load_rows(Ib, Jb, y0 - 3, col0);   // held
    Rows A   = load_rows(Ib, Jb, y0 - 2, col0);
    Rows B   = load_rows(Ib, Jb, y0 - 1, col0);

    ACC_ROWS(od0)
    ACC_ROWS(od1)
    ACC_ROWS(A)  A = load_rows(Ib, Jb, y0 + 0, col0);
    ACC_ROWS(B)  B = load_rows(Ib, Jb, y0 + 1, col0);
    ACC_ROWS(A)  A = load_rows(Ib, Jb, y0 + 2, col0);
    ACC_ROWS(B)  B = load_rows(Ib, Jb, y0 + 3, col0);
    ACC_ROWS(A)  A = load_rows(Ib, Jb, y0 + 4, col0);
    ACC_ROWS(B)  B = load_rows(Ib, Jb, y0 + 5, col0);   // nw0
    ACC_ROWS(A)  A = load_rows(Ib, Jb, y0 + 6, col0);   // nw1
    // sums now cover rows y0-4..y0+4; B=row y0+5, A=row y0+6 in flight.

    float local = 0.0f;

    // lean hpass: one shared transient, wI/wJ reused for Iv/Jv
    auto hpass = [&]() {
        float wI[8], wJ[8], t[8], cross[8];
        hwin(sI, lane, wI);
        hwin(sJ, lane, wJ);
        hwin(sIJ, lane, t);
        #pragma unroll
        for (int k = 0; k < 8; ++k)
            cross[k] = fmaxf(fmaf(-wI[k] * INV81, wJ[k], t[k]), EPS);
        hwin(sII, lane, t);
        #pragma unroll
        for (int k = 0; k < 8; ++k)
            wI[k] = fmaxf(fmaf(-wI[k] * INV81, wI[k], t[k]), EPS);   // Iv
        hwin(sJJ, lane, t);
        #pragma unroll
        for (int k = 0; k < 8; ++k)
            wJ[k] = fmaxf(fmaf(-wJ[k] * INV81, wJ[k], t[k]), EPS);   // Jv
        #pragma unroll
        for (int k = 0; k < 8; ++k)
            local += (cross[k] * cross[k]) * __builtin_amdgcn_rcpf(wI[k] * wJ[k]);
    };

    hpass();                               // row y0      (covers B,A loads)
    UPD_ROWS(B, od0)                       // +y0+5, -y0-4 (od0 freed)
    B = load_rows(Ib, Jb, y0 + 7, col0);   // nw2
    hpass();                               // row y0+1
    UPD_ROWS(A, od1)                       // +y0+6, -y0-3 (od1 freed)
    A = load_rows(Ib, Jb, y0 - 2, col0);   // od2 re-read (L2-resident)
    hpass();                               // row y0+2
    UPD_ROWS(B, A)                         // +y0+7, -y0-2
    hpass();                               // row y0+3

    // ---- wave reduction + intra-block LDS reduce (syncthreads-safe) ----
    #pragma unroll
    for (int off = 32; off > 0; off >>= 1)
        local += __shfl_down(local, off, 64);

    __shared__ float wpart[4];
    if (lane == 0) wpart[wid] = local;
    __syncthreads();
    if (threadIdx.x == 0) {
        double bsum = ((double)wpart[0] + (double)wpart[1]) +
                      ((double)wpart[2] + (double)wpart[3]);
        slots[blockIdx.x] = bsum;          // plain store; kernel boundary
    }                                      // publishes it to dispatch #2
}

__global__ __launch_bounds__(256) void ncc_finalize_kernel(
    const double* __restrict__ slots, float* __restrict__ out)
{
    const int tid = threadIdx.x;
    double2 v = *(const double2*)(slots + 2 * tid);   // 512 doubles total
    double t = v.x + v.y;
    #pragma unroll
    for (int off = 32; off > 0; off >>= 1)
        t += __shfl_down(t, off, 64);

    __shared__ double wsumd[4];
    if ((tid & 63) == 0) wsumd[tid >> 6] = t;
    __syncthreads();
    if (tid == 0)
        out[0] = (float)(-((wsumd[0] + wsumd[1]) +
                           (wsumd[2] + wsumd[3])) / NPIX);
}

extern "C" void kernel_launch(void* const* d_in, const int* in_sizes, int n_in,
                              void* d_out, int out_size, void* d_ws, size_t ws_size,
                              hipStream_t stream)
{
    const float* I = (const float*)d_in[0];   // y_true
    const float* J = (const float*)d_in[1];   // y_pred
    float* out = (float*)d_out;
    double* slots = (double*)d_ws;            // 512 doubles, all written each call

    ncc_band_kernel<<<NBLK, 256, 0, stream>>>(I, J, slots);
    ncc_finalize_kernel<<<1, 256, 0, stream>>>(slots, out);
}